// Round 12
// baseline (1201.704 us; speedup 1.0000x reference)
//
#include <hip/hip_runtime.h>
#include <hip/hip_cooperative_groups.h>

namespace cg = cooperative_groups;

typedef unsigned int u32;
typedef unsigned short u16;

#define NPB 64            // nodes per final bucket
#define CNTB 512          // blocks for partial histograms
#define MSEG 16           // row segments in merge
#define PCHUNK 4096       // edges per block in partition pass
#define SPB 16            // chunks per super-bucket in pass 2
#define DHCHUNK 8         // chunks per super in dest histogram
#define OUT_CHUNK 640

__device__ inline float bf2f(u16 b) { return __uint_as_float(((u32)b) << 16); }
__device__ inline u16 f2bf(float f) {
    u32 u = __float_as_uint(f);
    return (u16)((u + 0x7fffu + ((u >> 16) & 1u)) >> 16);   // RNE
}
__device__ inline u32 pack2(float a, float b) { return (u32)f2bf(a) | ((u32)f2bf(b) << 16); }

__global__ void k_zero_i(int* __restrict__ p, int n) {
    int i = blockIdx.x * 256 + threadIdx.x;
    if (i < n) p[i] = 0;
}

// ---------- partial histograms: source buckets (nbuckets) + dest supers (64), no global atomics
__global__ void k_cnt(const int* __restrict__ ei, int E,
                      int* __restrict__ pcnt, int nbuckets) {
    extern __shared__ int h[];            // [nbuckets + 64]
    int M = nbuckets + 64;
    for (int i = threadIdx.x; i < M; i += 256) h[i] = 0;
    __syncthreads();
    int stride = gridDim.x * 256;
    for (int e = blockIdx.x * 256 + threadIdx.x; e < E; e += stride) {
        atomicAdd(&h[ei[e] >> 6], 1);                   // source bucket
        atomicAdd(&h[nbuckets + (ei[E + e] >> 12)], 1); // dest super
    }
    __syncthreads();
    int* dst = pcnt + (size_t)blockIdx.x * M;
    for (int i = threadIdx.x; i < M; i += 256) dst[i] = h[i];
}

// ---------- merge partials: bin-parallel, 4 loads in flight, MSEG row-segments
__global__ void k_merge(const int* __restrict__ pcnt, int M, int nbuckets,
                        int* __restrict__ bcnt, int* __restrict__ dscnt) {
    int bin = blockIdx.x * 256 + threadIdx.x;
    if (bin >= M) return;
    const int per = CNTB / MSEG;          // 32 rows per segment
    const int* p = pcnt + (size_t)(blockIdx.y * per) * M + bin;
    int s0 = 0, s1 = 0, s2 = 0, s3 = 0;
    #pragma unroll
    for (int b = 0; b < per; b += 4) {
        s0 += p[(size_t)(b + 0) * M];
        s1 += p[(size_t)(b + 1) * M];
        s2 += p[(size_t)(b + 2) * M];
        s3 += p[(size_t)(b + 3) * M];
    }
    int s = s0 + s1 + s2 + s3;
    if (s) {
        if (bin < nbuckets) atomicAdd(&bcnt[bin], s);
        else atomicAdd(&dscnt[bin - nbuckets], s);
    }
}

// ---------- single-block chunked exclusive scan of bucket counts (+ dest-super scan)
__global__ void k_scanB(const int* __restrict__ bcnt, int nbuckets,
                        const int* __restrict__ dscnt,
                        int* __restrict__ boff, int* __restrict__ bCur,
                        int* __restrict__ soff, int* __restrict__ sCur,
                        int* __restrict__ dsoff, int* __restrict__ dsCur,
                        int* __restrict__ offsets, int N, int E, int nsup, int nsupD) {
    __shared__ int s[1024];
    __shared__ int carry;
    int t = threadIdx.x;
    if (t == 0) carry = 0;
    __syncthreads();
    for (int base = 0; base < nbuckets; base += 1024) {
        int i = base + t;
        int v = (i < nbuckets) ? bcnt[i] : 0;
        s[t] = v;
        __syncthreads();
        for (int off = 1; off < 1024; off <<= 1) {
            int tmp = (t >= off) ? s[t - off] : 0;
            __syncthreads();
            s[t] += tmp;
            __syncthreads();
        }
        int pos = s[t] - v + carry;
        if (i < nbuckets) {
            boff[i] = pos;
            bCur[i] = pos;
            if ((i & 63) == 0) { soff[i >> 6] = pos; sCur[i >> 6] = pos; }
        }
        __syncthreads();
        if (t == 1023) carry += s[1023];
        __syncthreads();
    }
    if (t == 0) {
        boff[nbuckets] = E; soff[nsup] = E; offsets[N] = E;
        int acc = 0;
        for (int i = 0; i < nsupD; ++i) {
            dsoff[i] = acc; dsCur[i] = acc;
            acc += dscnt[i];
        }
        dsoff[nsupD] = E;
    }
}

// ---------- fused partition: source supers (u32 payload) + dest supers (u16 payload)
__global__ __launch_bounds__(512) void k_part(const int* __restrict__ ei, int E,
                                              int* __restrict__ sCur, int* __restrict__ dsCur,
                                              u32* __restrict__ buf1, u16* __restrict__ dbuf) {
    __shared__ int cnt[64];
    __shared__ int cur[64];
    __shared__ int dcnt[64];
    __shared__ int dcur[64];
    int c0 = blockIdx.x * PCHUNK;
    int c1 = min(E, c0 + PCHUNK);
    int t = threadIdx.x;
    if (t < 64) { cnt[t] = 0; dcnt[t] = 0; }
    __syncthreads();
    for (int e = c0 + t; e < c1; e += 512) {
        atomicAdd(&cnt[ei[e] >> 12], 1);
        atomicAdd(&dcnt[ei[E + e] >> 12], 1);
    }
    __syncthreads();
    if (t < 64) {
        int c = cnt[t];
        cur[t] = c ? atomicAdd(&sCur[t], c) : 0;
        int dc = dcnt[t];
        dcur[t] = dc ? atomicAdd(&dsCur[t], dc) : 0;
    }
    __syncthreads();
    for (int e = c0 + t; e < c1; e += 512) {
        int s = ei[e];
        int d = ei[E + e];
        int p = atomicAdd(&cur[s >> 12], 1);
        buf1[p] = (u32)(d & 0x3FFFF) | ((u32)(s & 4095) << 18);
        int pd = atomicAdd(&dcur[d >> 12], 1);
        dbuf[pd] = (u16)(d & 4095);
    }
}

// ---------- dest histogram: per (super, chunk) LDS hist of 4096 bins -> coalesced atomic merge
__global__ __launch_bounds__(256) void k_dhist(const u16* __restrict__ dbuf,
                                               const int* __restrict__ dsoff,
                                               int* __restrict__ deg, int N) {
    __shared__ int h[4096];
    int sup = blockIdx.x / DHCHUNK;
    int ch = blockIdx.x % DHCHUNK;
    int t = threadIdx.x;
    for (int i = t; i < 4096; i += 256) h[i] = 0;
    __syncthreads();
    int s0 = dsoff[sup], s1 = dsoff[sup + 1];
    int per = (s1 - s0 + DHCHUNK - 1) / DHCHUNK;
    int c0 = s0 + ch * per;
    int c1 = min(s1, c0 + per);
    for (int e = c0 + t; e < c1; e += 256)
        atomicAdd(&h[dbuf[e]], 1);
    __syncthreads();
    int vbase = sup << 12;
    for (int i = t; i < 4096; i += 256) {
        int v = h[i];
        if (v && vbase + i < N) atomicAdd(&deg[vbase + i], v);
    }
}

// ---------- pass 2: within each source super, partition to the 64 final buckets
__global__ __launch_bounds__(256) void k_p2(const u32* __restrict__ buf1,
                                            const int* __restrict__ soff,
                                            int* __restrict__ bCur,
                                            u32* __restrict__ binned) {
    __shared__ int cnt[64];
    __shared__ int cur[64];
    int sb = blockIdx.x / SPB;
    int ch = blockIdx.x % SPB;
    int s0 = soff[sb], s1 = soff[sb + 1];
    int per = (s1 - s0 + SPB - 1) / SPB;
    int c0 = s0 + ch * per;
    int c1 = min(s1, c0 + per);
    int t = threadIdx.x;
    if (t < 64) cnt[t] = 0;
    __syncthreads();
    for (int e = c0 + t; e < c1; e += 256)
        atomicAdd(&cnt[(buf1[e] >> 24) & 63], 1);
    __syncthreads();
    if (t < 64) {
        int c = cnt[t];
        cur[t] = (c > 0) ? atomicAdd(&bCur[(sb << 6) + t], c) : 0;
    }
    __syncthreads();
    for (int e = c0 + t; e < c1; e += 256) {
        u32 v = buf1[e];
        int p = atomicAdd(&cur[(v >> 24) & 63], 1);
        binned[p] = v & 0x00FFFFFFu;     // dest(18b) | srclocal<<18
    }
}

// ---------- per-bucket counting sort -> dsts CSR (by source) + offsets
__global__ __launch_bounds__(256) void k_sort(const u32* __restrict__ binned,
                                              const int* __restrict__ boff,
                                              int* __restrict__ offsets,
                                              int* __restrict__ dsts, int N) {
    __shared__ int cnt[64];
    __shared__ int off[64];
    int b = blockIdx.x;
    int s0 = boff[b], s1 = boff[b + 1];
    int t = threadIdx.x;
    if (t < 64) cnt[t] = 0;
    __syncthreads();
    for (int e = s0 + t; e < s1; e += 256)
        atomicAdd(&cnt[(binned[e] >> 18) & 63], 1);
    __syncthreads();
    if (t == 0) {
        int acc = s0;
        #pragma unroll
        for (int i = 0; i < 64; ++i) { off[i] = acc; acc += cnt[i]; }
    }
    __syncthreads();
    int vbase = b << 6;
    if (t < 64 && vbase + t < N) offsets[vbase + t] = off[t];
    __syncthreads();
    if (t < 64) cnt[t] = off[t];
    __syncthreads();
    for (int e = s0 + t; e < s1; e += 256) {
        u32 v = binned[e];
        int p = atomicAdd(&cnt[(v >> 18) & 63], 1);
        dsts[p] = (int)(v & 0x3FFFFu);
    }
}

// dinv = rsqrt(deg+1); a = 0.9*dinv^2; rd = sqrt(deg+1)
__global__ void k_dinv(const int* __restrict__ deg, float* __restrict__ dinv,
                       float* __restrict__ a, float* __restrict__ rd, int N) {
    int i = blockIdx.x * 256 + threadIdx.x;
    if (i < N) {
        float d = (float)(deg[i] + 1);
        float dv = rsqrtf(d);
        dinv[i] = dv;
        a[i] = 0.9f * dv * dv;
        rd[i] = sqrtf(d);
    }
}

// ---------- A = emb @ W1.T  (per-gene, f32)
__global__ __launch_bounds__(256) void k_AW(const float* __restrict__ emb,
                                            const float* __restrict__ W1,
                                            float* __restrict__ A, int ngenes) {
    __shared__ float w1[32][33];
    __shared__ float eb[8][33];
    int t = threadIdx.x;
    int j = t & 31, gl = t >> 5;
    for (int i = t; i < 1024; i += 256) w1[i >> 5][i & 31] = W1[i];
    int g = blockIdx.x * 8 + gl;
    if (g < ngenes) eb[gl][j] = emb[g * 32 + j];
    __syncthreads();
    if (g < ngenes) {
        float acc = 0.f;
        #pragma unroll
        for (int c = 0; c < 32; ++c) acc = fmaf(eb[gl][c], w1[j][c], acc);
        A[(size_t)g * 32 + j] = acc;
    }
}

// s1[j] = rowsum of W1
__global__ void k_s1(const float* __restrict__ W1, float* __restrict__ s1) {
    int j = threadIdx.x;
    if (j < 32) {
        float acc = 0.f;
        #pragma unroll
        for (int c = 0; c < 32; ++c) acc += W1[j * 32 + c];
        s1[j] = acc;
    }
}

// ---------- fused MLP -> h0 (bf16, unscaled) + q0 = dinv*e_b (bf16) + zero out
__global__ __launch_bounds__(256) void k_h0(const float* __restrict__ x,
                                            const float* __restrict__ A,
                                            const float* __restrict__ bias,
                                            const float* __restrict__ s1,
                                            const float* __restrict__ b1,
                                            const float* __restrict__ W2,
                                            const float* __restrict__ b2,
                                            const float* __restrict__ dinv,
                                            uint4* __restrict__ h0,
                                            uint4* __restrict__ q0,
                                            float* __restrict__ out, int out_n,
                                            int N, int ngenes) {
    int node = blockIdx.x * 256 + threadIdx.x;
    if (blockIdx.x == 0 && threadIdx.x < out_n) out[threadIdx.x] = 0.f;
    if (node >= N) return;
    int g = node % ngenes;
    float xv = x[node];
    float bv = bias[g];
    const float4* Ar = (const float4*)(A + (size_t)g * 32);
    float r1[32];
    #pragma unroll
    for (int q = 0; q < 8; ++q) {
        float4 a4 = Ar[q];
        r1[q * 4 + 0] = fmaxf(fmaf(xv, a4.x, fmaf(bv, s1[q * 4 + 0], b1[q * 4 + 0])), 0.f);
        r1[q * 4 + 1] = fmaxf(fmaf(xv, a4.y, fmaf(bv, s1[q * 4 + 1], b1[q * 4 + 1])), 0.f);
        r1[q * 4 + 2] = fmaxf(fmaf(xv, a4.z, fmaf(bv, s1[q * 4 + 2], b1[q * 4 + 2])), 0.f);
        r1[q * 4 + 3] = fmaxf(fmaf(xv, a4.w, fmaf(bv, s1[q * 4 + 3], b1[q * 4 + 3])), 0.f);
    }
    u32 ow[16];
    #pragma unroll
    for (int i = 0; i < 32; i += 2) {
        float accA = b2[i];
        float accB = b2[i + 1];
        #pragma unroll
        for (int j2 = 0; j2 < 32; ++j2) {
            accA = fmaf(r1[j2], W2[i * 32 + j2], accA);
            accB = fmaf(r1[j2], W2[(i + 1) * 32 + j2], accB);
        }
        ow[i >> 1] = pack2(accA, accB);
    }
    #pragma unroll
    for (int q = 0; q < 4; ++q) {
        uint4 o;
        o.x = ow[q * 4 + 0];
        o.y = ow[q * 4 + 1];
        o.z = ow[q * 4 + 2];
        o.w = ow[q * 4 + 3];
        h0[(size_t)node * 4 + q] = o;
    }
    int gb = node / ngenes;
    u32 lo = (u32)f2bf(dinv[node]);
    u32 hi = lo << 16;
    uint4 qo;
    qo.x = (gb == 0) ? lo : (gb == 1) ? hi : 0u;
    qo.y = (gb == 2) ? lo : (gb == 3) ? hi : 0u;
    qo.z = (gb == 4) ? lo : (gb == 5) ? hi : 0u;
    qo.w = (gb == 6) ? lo : (gb == 7) ? hi : 0u;
    q0[node] = qo;
}

// ---------- ALL 10 reverse-APPNP steps in one cooperative kernel (persistent, grid.sync)
// qA holds q0 on entry and the final state on exit (steps must be even).
__global__ __launch_bounds__(256) void k_propN(uint4* __restrict__ qAb,
                                               uint4* __restrict__ qBb,
                                               const float* __restrict__ a,
                                               const float* __restrict__ dinv,
                                               const int* __restrict__ offsets,
                                               const int* __restrict__ dsts,
                                               int N, int ngenes, int steps) {
    cg::grid_group grid = cg::this_grid();
    int node = blockIdx.x * 256 + threadIdx.x;
    bool active = node < N;
    int s0 = 0, s1 = 0;
    float av = 0.f, i0 = 0.f, i1 = 0.f, i2 = 0.f, i3 = 0.f, i4 = 0.f, i5 = 0.f, i6 = 0.f, i7 = 0.f;
    if (active) {
        s0 = offsets[node];
        s1 = offsets[node + 1];
        av = a[node];
        float qi = 0.1f * dinv[node];
        int gb = node / ngenes;
        i0 = (gb == 0) ? qi : 0.f;
        i1 = (gb == 1) ? qi : 0.f;
        i2 = (gb == 2) ? qi : 0.f;
        i3 = (gb == 3) ? qi : 0.f;
        i4 = (gb == 4) ? qi : 0.f;
        i5 = (gb == 5) ? qi : 0.f;
        i6 = (gb == 6) ? qi : 0.f;
        i7 = (gb == 7) ? qi : 0.f;
    }
    const uint4* qin = qAb;
    uint4* qout = qBb;
    for (int it = 0; it < steps; ++it) {
        if (active) {
            uint4 self = qin[node];
            float c0 = bf2f((u16)self.x), c1 = bf2f((u16)(self.x >> 16));
            float c2 = bf2f((u16)self.y), c3 = bf2f((u16)(self.y >> 16));
            float c4 = bf2f((u16)self.z), c5 = bf2f((u16)(self.z >> 16));
            float c6 = bf2f((u16)self.w), c7 = bf2f((u16)(self.w >> 16));
            int e = s0;
            for (; e + 4 <= s1; e += 4) {
                uint4 vA = qin[dsts[e]];
                uint4 vB = qin[dsts[e + 1]];
                uint4 vC = qin[dsts[e + 2]];
                uint4 vD = qin[dsts[e + 3]];
                c0 += bf2f((u16)vA.x) + bf2f((u16)vB.x) + bf2f((u16)vC.x) + bf2f((u16)vD.x);
                c1 += bf2f((u16)(vA.x >> 16)) + bf2f((u16)(vB.x >> 16)) + bf2f((u16)(vC.x >> 16)) + bf2f((u16)(vD.x >> 16));
                c2 += bf2f((u16)vA.y) + bf2f((u16)vB.y) + bf2f((u16)vC.y) + bf2f((u16)vD.y);
                c3 += bf2f((u16)(vA.y >> 16)) + bf2f((u16)(vB.y >> 16)) + bf2f((u16)(vC.y >> 16)) + bf2f((u16)(vD.y >> 16));
                c4 += bf2f((u16)vA.z) + bf2f((u16)vB.z) + bf2f((u16)vC.z) + bf2f((u16)vD.z);
                c5 += bf2f((u16)(vA.z >> 16)) + bf2f((u16)(vB.z >> 16)) + bf2f((u16)(vC.z >> 16)) + bf2f((u16)(vD.z >> 16));
                c6 += bf2f((u16)vA.w) + bf2f((u16)vB.w) + bf2f((u16)vC.w) + bf2f((u16)vD.w);
                c7 += bf2f((u16)(vA.w >> 16)) + bf2f((u16)(vB.w >> 16)) + bf2f((u16)(vC.w >> 16)) + bf2f((u16)(vD.w >> 16));
            }
            for (; e < s1; ++e) {
                uint4 v = qin[dsts[e]];
                c0 += bf2f((u16)v.x); c1 += bf2f((u16)(v.x >> 16));
                c2 += bf2f((u16)v.y); c3 += bf2f((u16)(v.y >> 16));
                c4 += bf2f((u16)v.z); c5 += bf2f((u16)(v.z >> 16));
                c6 += bf2f((u16)v.w); c7 += bf2f((u16)(v.w >> 16));
            }
            uint4 o;
            o.x = pack2(fmaf(av, c0, i0), fmaf(av, c1, i1));
            o.y = pack2(fmaf(av, c2, i2), fmaf(av, c3, i3));
            o.z = pack2(fmaf(av, c4, i4), fmaf(av, c5, i5));
            o.w = pack2(fmaf(av, c6, i6), fmaf(av, c7, i7));
            qout[node] = o;
        }
        grid.sync();
        const uint4* tmp = qout;
        qout = (uint4*)qin;
        qin = tmp;
    }
}

// ---------- contraction: out[b][c] = (1/ngenes) sum_v q[v][b]*rd[v]*h0[v][c]
__global__ __launch_bounds__(256) void k_out(const uint4* __restrict__ q,
                                             const u16* __restrict__ h0,
                                             const float* __restrict__ rd,
                                             float* __restrict__ out,
                                             int N, int ngenes) {
    __shared__ float wq[64][8];
    __shared__ u16 hs[64][32];
    int t = threadIdx.x;
    int b = t >> 5, c = t & 31;
    float acc = 0.f;
    int base = blockIdx.x * OUT_CHUNK;
    int lim = min(N, base + OUT_CHUNK);
    for (int v0 = base; v0 < lim; v0 += 64) {
        int nv = min(64, lim - v0);
        __syncthreads();
        int r = t >> 2, w4 = t & 3;
        if (r < nv) {
            *(uint4*)&hs[r][w4 * 8] = ((const uint4*)(h0 + (size_t)(v0 + r) * 32))[w4];
            u32 wv = ((const u32*)&q[v0 + r])[w4];
            float rdv = rd[v0 + r];
            wq[r][w4 * 2] = bf2f((u16)wv) * rdv;
            wq[r][w4 * 2 + 1] = bf2f((u16)(wv >> 16)) * rdv;
        }
        __syncthreads();
        for (int i = 0; i < nv; ++i)
            acc = fmaf(wq[i][b], bf2f(hs[i][c]), acc);
    }
    atomicAdd(&out[b * 32 + c], acc / (float)ngenes);
}

extern "C" void kernel_launch(void* const* d_in, const int* in_sizes, int n_in,
                              void* d_out, int out_size, void* d_ws, size_t ws_size,
                              hipStream_t stream) {
    const float* x    = (const float*)d_in[0];
    const int*   ei   = (const int*)d_in[1];   // [2,E]: row at [0,E), col at [E,2E)
    const float* emb  = (const float*)d_in[3];
    const float* bias = (const float*)d_in[4];
    const float* W1   = (const float*)d_in[5];
    const float* b1   = (const float*)d_in[6];
    const float* W2   = (const float*)d_in[7];
    const float* b2   = (const float*)d_in[8];
    float* out = (float*)d_out;

    int N = in_sizes[0];
    int E = in_sizes[1] / 2;
    int ngenes = in_sizes[4];
    int nbuckets = (N + NPB - 1) / NPB;        // 2500
    int nsup = (nbuckets + 63) / 64;           // 40 (source supers)
    int nsupD = (N + 4095) / 4096;             // 40 (dest supers)
    int M = nbuckets + 64;

    char* pws = (char*)d_ws;
    auto carve = [&](size_t bytes) {
        void* r = (void*)pws;
        pws += (bytes + 255) & ~(size_t)255;
        return r;
    };
    u16*   h0      = (u16*)carve((size_t)N * 32 * 2);
    uint4* qA      = (uint4*)carve((size_t)N * 16);
    uint4* qB      = (uint4*)carve((size_t)N * 16);
    float* Amat    = (float*)carve((size_t)ngenes * 32 * 4);
    float* s1v     = (float*)carve(32 * 4);
    float* dinv    = (float*)carve((size_t)N * 4);
    float* afac    = (float*)carve((size_t)N * 4);
    float* rd      = (float*)carve((size_t)N * 4);
    int*   offsets = (int*)carve((size_t)(N + 1) * 4);
    int*   deg     = (int*)carve((size_t)N * 4);
    int*   bcnt    = (int*)carve((size_t)nbuckets * 4);
    int*   dscnt   = (int*)carve(64 * 4);
    int*   boff    = (int*)carve((size_t)(nbuckets + 1) * 4);
    int*   bCur    = (int*)carve((size_t)nbuckets * 4);
    int*   soff    = (int*)carve(65 * 4);
    int*   sCur    = (int*)carve(64 * 4);
    int*   dsoff   = (int*)carve(65 * 4);
    int*   dsCur   = (int*)carve(64 * 4);
    int*   pcnt    = (int*)carve((size_t)CNTB * M * 4);
    u32*   buf1    = (u32*)carve((size_t)E * 4);
    u32*   binned  = (u32*)carve((size_t)E * 4);
    int*   dsts    = (int*)carve((size_t)E * 4);
    u16*   dbuf    = (u16*)carve((size_t)E * 2);

    int nbN = (N + 255) / 256;
    int zlen = (int)(dscnt - deg) + 64;        // deg..bcnt..dscnt contiguous carves

    hipLaunchKernelGGL(k_zero_i, dim3((zlen + 255) / 256), dim3(256), 0, stream, deg, zlen);
    hipLaunchKernelGGL(k_cnt, dim3(CNTB), dim3(256), M * 4, stream, ei, E, pcnt, nbuckets);
    hipLaunchKernelGGL(k_merge, dim3((M + 255) / 256, MSEG), dim3(256), 0, stream,
                       pcnt, M, nbuckets, bcnt, dscnt);
    hipLaunchKernelGGL(k_scanB, dim3(1), dim3(1024), 0, stream,
                       bcnt, nbuckets, dscnt, boff, bCur, soff, sCur, dsoff, dsCur,
                       offsets, N, E, nsup, nsupD);
    hipLaunchKernelGGL(k_part, dim3((E + PCHUNK - 1) / PCHUNK), dim3(512), 0, stream,
                       ei, E, sCur, dsCur, buf1, dbuf);
    hipLaunchKernelGGL(k_dhist, dim3(nsupD * DHCHUNK), dim3(256), 0, stream,
                       dbuf, dsoff, deg, N);
    hipLaunchKernelGGL(k_dinv, dim3(nbN), dim3(256), 0, stream, deg, dinv, afac, rd, N);
    hipLaunchKernelGGL(k_p2, dim3(nsup * SPB), dim3(256), 0, stream, buf1, soff, bCur, binned);
    hipLaunchKernelGGL(k_sort, dim3(nbuckets), dim3(256), 0, stream,
                       binned, boff, offsets, dsts, N);
    hipLaunchKernelGGL(k_AW, dim3((ngenes + 7) / 8), dim3(256), 0, stream, emb, W1, Amat, ngenes);
    hipLaunchKernelGGL(k_s1, dim3(1), dim3(64), 0, stream, W1, s1v);
    hipLaunchKernelGGL(k_h0, dim3(nbN), dim3(256), 0, stream,
                       x, Amat, bias, s1v, b1, W2, b2, dinv,
                       (uint4*)h0, qA, out, out_size, N, ngenes);

    // 10 propagation steps in one cooperative launch (even count -> result lands in qA)
    int steps = 10;
    void* args[] = { (void*)&qA, (void*)&qB, (void*)&afac, (void*)&dinv,
                     (void*)&offsets, (void*)&dsts, (void*)&N, (void*)&ngenes, (void*)&steps };
    hipLaunchCooperativeKernel((const void*)k_propN, dim3(nbN), dim3(256), args, 0, stream);

    hipLaunchKernelGGL(k_out, dim3((N + OUT_CHUNK - 1) / OUT_CHUNK), dim3(256), 0, stream,
                       qA, h0, rd, out, N, ngenes);
}

// Round 13
// 351.188 us; speedup vs baseline: 3.4218x; 3.4218x over previous
//
#include <hip/hip_runtime.h>

typedef unsigned int u32;
typedef unsigned short u16;

#define NPB 64            // nodes per final bucket
#define CNTB 512          // blocks for partial histograms
#define MSEG 16           // row segments in merge
#define PCHUNK 4096       // edges per block in partition pass
#define SPB 16            // chunks per super-bucket in pass 2
#define DHCHUNK 8         // chunks per super in dest histogram
#define OUT_CHUNK 640

__device__ inline float bf2f(u16 b) { return __uint_as_float(((u32)b) << 16); }
__device__ inline u16 f2bf(float f) {
    u32 u = __float_as_uint(f);
    return (u16)((u + 0x7fffu + ((u >> 16) & 1u)) >> 16);   // RNE
}
__device__ inline u32 pack2(float a, float b) { return (u32)f2bf(a) | ((u32)f2bf(b) << 16); }

__global__ void k_zero_i(int* __restrict__ p, int n) {
    int i = blockIdx.x * 256 + threadIdx.x;
    if (i < n) p[i] = 0;
}

// ---------- partial histograms: source buckets (nbuckets) + dest supers (64), no global atomics
__global__ void k_cnt(const int* __restrict__ ei, int E,
                      int* __restrict__ pcnt, int nbuckets) {
    extern __shared__ int h[];            // [nbuckets + 64]
    int M = nbuckets + 64;
    for (int i = threadIdx.x; i < M; i += 256) h[i] = 0;
    __syncthreads();
    int stride = gridDim.x * 256;
    for (int e = blockIdx.x * 256 + threadIdx.x; e < E; e += stride) {
        atomicAdd(&h[ei[e] >> 6], 1);                   // source bucket
        atomicAdd(&h[nbuckets + (ei[E + e] >> 12)], 1); // dest super
    }
    __syncthreads();
    int* dst = pcnt + (size_t)blockIdx.x * M;
    for (int i = threadIdx.x; i < M; i += 256) dst[i] = h[i];
}

// ---------- merge partials: bin-parallel, 4 loads in flight, MSEG row-segments
__global__ void k_merge(const int* __restrict__ pcnt, int M, int nbuckets,
                        int* __restrict__ bcnt, int* __restrict__ dscnt) {
    int bin = blockIdx.x * 256 + threadIdx.x;
    if (bin >= M) return;
    const int per = CNTB / MSEG;          // 32 rows per segment
    const int* p = pcnt + (size_t)(blockIdx.y * per) * M + bin;
    int s0 = 0, s1 = 0, s2 = 0, s3 = 0;
    #pragma unroll
    for (int b = 0; b < per; b += 4) {
        s0 += p[(size_t)(b + 0) * M];
        s1 += p[(size_t)(b + 1) * M];
        s2 += p[(size_t)(b + 2) * M];
        s3 += p[(size_t)(b + 3) * M];
    }
    int s = s0 + s1 + s2 + s3;
    if (s) {
        if (bin < nbuckets) atomicAdd(&bcnt[bin], s);
        else atomicAdd(&dscnt[bin - nbuckets], s);
    }
}

// ---------- single-block chunked exclusive scan of bucket counts (+ dest-super scan)
__global__ void k_scanB(const int* __restrict__ bcnt, int nbuckets,
                        const int* __restrict__ dscnt,
                        int* __restrict__ boff, int* __restrict__ bCur,
                        int* __restrict__ soff, int* __restrict__ sCur,
                        int* __restrict__ dsoff, int* __restrict__ dsCur,
                        int* __restrict__ offsets, int N, int E, int nsup, int nsupD) {
    __shared__ int s[1024];
    __shared__ int carry;
    int t = threadIdx.x;
    if (t == 0) carry = 0;
    __syncthreads();
    for (int base = 0; base < nbuckets; base += 1024) {
        int i = base + t;
        int v = (i < nbuckets) ? bcnt[i] : 0;
        s[t] = v;
        __syncthreads();
        for (int off = 1; off < 1024; off <<= 1) {
            int tmp = (t >= off) ? s[t - off] : 0;
            __syncthreads();
            s[t] += tmp;
            __syncthreads();
        }
        int pos = s[t] - v + carry;
        if (i < nbuckets) {
            boff[i] = pos;
            bCur[i] = pos;
            if ((i & 63) == 0) { soff[i >> 6] = pos; sCur[i >> 6] = pos; }
        }
        __syncthreads();
        if (t == 1023) carry += s[1023];
        __syncthreads();
    }
    if (t == 0) {
        boff[nbuckets] = E; soff[nsup] = E; offsets[N] = E;
        int acc = 0;
        for (int i = 0; i < nsupD; ++i) {
            dsoff[i] = acc; dsCur[i] = acc;
            acc += dscnt[i];
        }
        dsoff[nsupD] = E;
    }
}

// ---------- fused partition: source supers (u32 payload) + dest supers (u16 payload)
__global__ __launch_bounds__(512) void k_part(const int* __restrict__ ei, int E,
                                              int* __restrict__ sCur, int* __restrict__ dsCur,
                                              u32* __restrict__ buf1, u16* __restrict__ dbuf) {
    __shared__ int cnt[64];
    __shared__ int cur[64];
    __shared__ int dcnt[64];
    __shared__ int dcur[64];
    int c0 = blockIdx.x * PCHUNK;
    int c1 = min(E, c0 + PCHUNK);
    int t = threadIdx.x;
    if (t < 64) { cnt[t] = 0; dcnt[t] = 0; }
    __syncthreads();
    for (int e = c0 + t; e < c1; e += 512) {
        atomicAdd(&cnt[ei[e] >> 12], 1);
        atomicAdd(&dcnt[ei[E + e] >> 12], 1);
    }
    __syncthreads();
    if (t < 64) {
        int c = cnt[t];
        cur[t] = c ? atomicAdd(&sCur[t], c) : 0;
        int dc = dcnt[t];
        dcur[t] = dc ? atomicAdd(&dsCur[t], dc) : 0;
    }
    __syncthreads();
    for (int e = c0 + t; e < c1; e += 512) {
        int s = ei[e];
        int d = ei[E + e];
        int p = atomicAdd(&cur[s >> 12], 1);
        buf1[p] = (u32)(d & 0x3FFFF) | ((u32)(s & 4095) << 18);
        int pd = atomicAdd(&dcur[d >> 12], 1);
        dbuf[pd] = (u16)(d & 4095);
    }
}

// ---------- dest histogram: per (super, chunk) LDS hist of 4096 bins -> coalesced atomic merge
__global__ __launch_bounds__(256) void k_dhist(const u16* __restrict__ dbuf,
                                               const int* __restrict__ dsoff,
                                               int* __restrict__ deg, int N) {
    __shared__ int h[4096];
    int sup = blockIdx.x / DHCHUNK;
    int ch = blockIdx.x % DHCHUNK;
    int t = threadIdx.x;
    for (int i = t; i < 4096; i += 256) h[i] = 0;
    __syncthreads();
    int s0 = dsoff[sup], s1 = dsoff[sup + 1];
    int per = (s1 - s0 + DHCHUNK - 1) / DHCHUNK;
    int c0 = s0 + ch * per;
    int c1 = min(s1, c0 + per);
    for (int e = c0 + t; e < c1; e += 256)
        atomicAdd(&h[dbuf[e]], 1);
    __syncthreads();
    int vbase = sup << 12;
    for (int i = t; i < 4096; i += 256) {
        int v = h[i];
        if (v && vbase + i < N) atomicAdd(&deg[vbase + i], v);
    }
}

// ---------- pass 2: within each source super, partition to the 64 final buckets
__global__ __launch_bounds__(256) void k_p2(const u32* __restrict__ buf1,
                                            const int* __restrict__ soff,
                                            int* __restrict__ bCur,
                                            u32* __restrict__ binned) {
    __shared__ int cnt[64];
    __shared__ int cur[64];
    int sb = blockIdx.x / SPB;
    int ch = blockIdx.x % SPB;
    int s0 = soff[sb], s1 = soff[sb + 1];
    int per = (s1 - s0 + SPB - 1) / SPB;
    int c0 = s0 + ch * per;
    int c1 = min(s1, c0 + per);
    int t = threadIdx.x;
    if (t < 64) cnt[t] = 0;
    __syncthreads();
    for (int e = c0 + t; e < c1; e += 256)
        atomicAdd(&cnt[(buf1[e] >> 24) & 63], 1);
    __syncthreads();
    if (t < 64) {
        int c = cnt[t];
        cur[t] = (c > 0) ? atomicAdd(&bCur[(sb << 6) + t], c) : 0;
    }
    __syncthreads();
    for (int e = c0 + t; e < c1; e += 256) {
        u32 v = buf1[e];
        int p = atomicAdd(&cur[(v >> 24) & 63], 1);
        binned[p] = v & 0x00FFFFFFu;     // dest(18b) | srclocal<<18
    }
}

// ---------- per-bucket counting sort -> dsts CSR (by source) + offsets
__global__ __launch_bounds__(256) void k_sort(const u32* __restrict__ binned,
                                              const int* __restrict__ boff,
                                              int* __restrict__ offsets,
                                              int* __restrict__ dsts, int N) {
    __shared__ int cnt[64];
    __shared__ int off[64];
    int b = blockIdx.x;
    int s0 = boff[b], s1 = boff[b + 1];
    int t = threadIdx.x;
    if (t < 64) cnt[t] = 0;
    __syncthreads();
    for (int e = s0 + t; e < s1; e += 256)
        atomicAdd(&cnt[(binned[e] >> 18) & 63], 1);
    __syncthreads();
    if (t == 0) {
        int acc = s0;
        #pragma unroll
        for (int i = 0; i < 64; ++i) { off[i] = acc; acc += cnt[i]; }
    }
    __syncthreads();
    int vbase = b << 6;
    if (t < 64 && vbase + t < N) offsets[vbase + t] = off[t];
    __syncthreads();
    if (t < 64) cnt[t] = off[t];
    __syncthreads();
    for (int e = s0 + t; e < s1; e += 256) {
        u32 v = binned[e];
        int p = atomicAdd(&cnt[(v >> 18) & 63], 1);
        dsts[p] = (int)(v & 0x3FFFFu);
    }
}

// ---------- A = emb @ W1.T (per-gene, f32); block 0 also emits s1 = rowsum(W1)
__global__ __launch_bounds__(256) void k_AW(const float* __restrict__ emb,
                                            const float* __restrict__ W1,
                                            float* __restrict__ A,
                                            float* __restrict__ s1, int ngenes) {
    __shared__ float w1[32][33];
    __shared__ float eb[8][33];
    int t = threadIdx.x;
    int j = t & 31, gl = t >> 5;
    for (int i = t; i < 1024; i += 256) w1[i >> 5][i & 31] = W1[i];
    int g = blockIdx.x * 8 + gl;
    if (g < ngenes) eb[gl][j] = emb[g * 32 + j];
    __syncthreads();
    if (blockIdx.x == 0 && t < 32) {
        float acc = 0.f;
        #pragma unroll
        for (int c = 0; c < 32; ++c) acc += w1[t][c];
        s1[t] = acc;
    }
    if (g < ngenes) {
        float acc = 0.f;
        #pragma unroll
        for (int c = 0; c < 32; ++c) acc = fmaf(eb[gl][c], w1[j][c], acc);
        A[(size_t)g * 32 + j] = acc;
    }
}

// ---------- fused: dinv/afac/rd from deg + MLP -> h0 (bf16) + q0 = dinv*e_b + zero out
__global__ __launch_bounds__(256) void k_h0(const float* __restrict__ x,
                                            const float* __restrict__ A,
                                            const float* __restrict__ bias,
                                            const float* __restrict__ s1,
                                            const float* __restrict__ b1,
                                            const float* __restrict__ W2,
                                            const float* __restrict__ b2,
                                            const int* __restrict__ deg,
                                            float* __restrict__ dinv,
                                            float* __restrict__ afac,
                                            float* __restrict__ rd,
                                            uint4* __restrict__ h0,
                                            uint4* __restrict__ q0,
                                            float* __restrict__ out, int out_n,
                                            int N, int ngenes) {
    int node = blockIdx.x * 256 + threadIdx.x;
    if (blockIdx.x == 0 && threadIdx.x < out_n) out[threadIdx.x] = 0.f;
    if (node >= N) return;
    float d = (float)(deg[node] + 1);
    float dv = rsqrtf(d);
    dinv[node] = dv;
    afac[node] = 0.9f * dv * dv;
    rd[node] = sqrtf(d);
    int g = node % ngenes;
    float xv = x[node];
    float bv = bias[g];
    const float4* Ar = (const float4*)(A + (size_t)g * 32);
    float r1[32];
    #pragma unroll
    for (int q = 0; q < 8; ++q) {
        float4 a4 = Ar[q];
        r1[q * 4 + 0] = fmaxf(fmaf(xv, a4.x, fmaf(bv, s1[q * 4 + 0], b1[q * 4 + 0])), 0.f);
        r1[q * 4 + 1] = fmaxf(fmaf(xv, a4.y, fmaf(bv, s1[q * 4 + 1], b1[q * 4 + 1])), 0.f);
        r1[q * 4 + 2] = fmaxf(fmaf(xv, a4.z, fmaf(bv, s1[q * 4 + 2], b1[q * 4 + 2])), 0.f);
        r1[q * 4 + 3] = fmaxf(fmaf(xv, a4.w, fmaf(bv, s1[q * 4 + 3], b1[q * 4 + 3])), 0.f);
    }
    u32 ow[16];
    #pragma unroll
    for (int i = 0; i < 32; i += 2) {
        float accA = b2[i];
        float accB = b2[i + 1];
        #pragma unroll
        for (int j2 = 0; j2 < 32; ++j2) {
            accA = fmaf(r1[j2], W2[i * 32 + j2], accA);
            accB = fmaf(r1[j2], W2[(i + 1) * 32 + j2], accB);
        }
        ow[i >> 1] = pack2(accA, accB);
    }
    #pragma unroll
    for (int q = 0; q < 4; ++q) {
        uint4 o;
        o.x = ow[q * 4 + 0];
        o.y = ow[q * 4 + 1];
        o.z = ow[q * 4 + 2];
        o.w = ow[q * 4 + 3];
        h0[(size_t)node * 4 + q] = o;
    }
    int gb = node / ngenes;
    u32 lo = (u32)f2bf(dv);
    u32 hi = lo << 16;
    uint4 qo;
    qo.x = (gb == 0) ? lo : (gb == 1) ? hi : 0u;
    qo.y = (gb == 2) ? lo : (gb == 3) ? hi : 0u;
    qo.z = (gb == 4) ? lo : (gb == 5) ? hi : 0u;
    qo.w = (gb == 6) ? lo : (gb == 7) ? hi : 0u;
    q0[node] = qo;
}

// ---------- one reverse-APPNP step on 8-channel state q (bf16, 16B/node), 8 gathers in flight
__device__ inline void qacc(const uint4& v, float& c0, float& c1, float& c2, float& c3,
                            float& c4, float& c5, float& c6, float& c7) {
    c0 += bf2f((u16)v.x); c1 += bf2f((u16)(v.x >> 16));
    c2 += bf2f((u16)v.y); c3 += bf2f((u16)(v.y >> 16));
    c4 += bf2f((u16)v.z); c5 += bf2f((u16)(v.z >> 16));
    c6 += bf2f((u16)v.w); c7 += bf2f((u16)(v.w >> 16));
}

__global__ __launch_bounds__(256) void k_prop8(const uint4* __restrict__ qin,
                                               uint4* __restrict__ qout,
                                               const float* __restrict__ a,
                                               const float* __restrict__ dinv,
                                               const int* __restrict__ offsets,
                                               const int* __restrict__ dsts,
                                               int N, int ngenes) {
    int node = blockIdx.x * 256 + threadIdx.x;
    if (node >= N) return;
    int s0 = offsets[node];
    int s1 = offsets[node + 1];
    uint4 self = qin[node];
    float c0 = bf2f((u16)self.x), c1 = bf2f((u16)(self.x >> 16));
    float c2 = bf2f((u16)self.y), c3 = bf2f((u16)(self.y >> 16));
    float c4 = bf2f((u16)self.z), c5 = bf2f((u16)(self.z >> 16));
    float c6 = bf2f((u16)self.w), c7 = bf2f((u16)(self.w >> 16));
    int e = s0;
    for (; e + 8 <= s1; e += 8) {
        int d0 = dsts[e + 0], d1 = dsts[e + 1], d2 = dsts[e + 2], d3 = dsts[e + 3];
        int d4 = dsts[e + 4], d5 = dsts[e + 5], d6 = dsts[e + 6], d7 = dsts[e + 7];
        uint4 v0 = qin[d0];
        uint4 v1 = qin[d1];
        uint4 v2 = qin[d2];
        uint4 v3 = qin[d3];
        uint4 v4 = qin[d4];
        uint4 v5 = qin[d5];
        uint4 v6 = qin[d6];
        uint4 v7 = qin[d7];
        qacc(v0, c0, c1, c2, c3, c4, c5, c6, c7);
        qacc(v1, c0, c1, c2, c3, c4, c5, c6, c7);
        qacc(v2, c0, c1, c2, c3, c4, c5, c6, c7);
        qacc(v3, c0, c1, c2, c3, c4, c5, c6, c7);
        qacc(v4, c0, c1, c2, c3, c4, c5, c6, c7);
        qacc(v5, c0, c1, c2, c3, c4, c5, c6, c7);
        qacc(v6, c0, c1, c2, c3, c4, c5, c6, c7);
        qacc(v7, c0, c1, c2, c3, c4, c5, c6, c7);
    }
    if (e + 4 <= s1) {
        int d0 = dsts[e + 0], d1 = dsts[e + 1], d2 = dsts[e + 2], d3 = dsts[e + 3];
        uint4 v0 = qin[d0];
        uint4 v1 = qin[d1];
        uint4 v2 = qin[d2];
        uint4 v3 = qin[d3];
        qacc(v0, c0, c1, c2, c3, c4, c5, c6, c7);
        qacc(v1, c0, c1, c2, c3, c4, c5, c6, c7);
        qacc(v2, c0, c1, c2, c3, c4, c5, c6, c7);
        qacc(v3, c0, c1, c2, c3, c4, c5, c6, c7);
        e += 4;
    }
    for (; e < s1; ++e) {
        uint4 v = qin[dsts[e]];
        qacc(v, c0, c1, c2, c3, c4, c5, c6, c7);
    }
    float av = a[node];
    float qi = 0.1f * dinv[node];
    int gb = node / ngenes;
    c0 = av * c0 + ((gb == 0) ? qi : 0.f);
    c1 = av * c1 + ((gb == 1) ? qi : 0.f);
    c2 = av * c2 + ((gb == 2) ? qi : 0.f);
    c3 = av * c3 + ((gb == 3) ? qi : 0.f);
    c4 = av * c4 + ((gb == 4) ? qi : 0.f);
    c5 = av * c5 + ((gb == 5) ? qi : 0.f);
    c6 = av * c6 + ((gb == 6) ? qi : 0.f);
    c7 = av * c7 + ((gb == 7) ? qi : 0.f);
    uint4 o;
    o.x = pack2(c0, c1);
    o.y = pack2(c2, c3);
    o.z = pack2(c4, c5);
    o.w = pack2(c6, c7);
    qout[node] = o;
}

// ---------- contraction: out[b][c] = (1/ngenes) sum_v q[v][b]*rd[v]*h0[v][c]
__global__ __launch_bounds__(256) void k_out(const uint4* __restrict__ q,
                                             const u16* __restrict__ h0,
                                             const float* __restrict__ rd,
                                             float* __restrict__ out,
                                             int N, int ngenes) {
    __shared__ float wq[64][8];
    __shared__ u16 hs[64][32];
    int t = threadIdx.x;
    int b = t >> 5, c = t & 31;
    float acc = 0.f;
    int base = blockIdx.x * OUT_CHUNK;
    int lim = min(N, base + OUT_CHUNK);
    for (int v0 = base; v0 < lim; v0 += 64) {
        int nv = min(64, lim - v0);
        __syncthreads();
        int r = t >> 2, w4 = t & 3;
        if (r < nv) {
            *(uint4*)&hs[r][w4 * 8] = ((const uint4*)(h0 + (size_t)(v0 + r) * 32))[w4];
            u32 wv = ((const u32*)&q[v0 + r])[w4];
            float rdv = rd[v0 + r];
            wq[r][w4 * 2] = bf2f((u16)wv) * rdv;
            wq[r][w4 * 2 + 1] = bf2f((u16)(wv >> 16)) * rdv;
        }
        __syncthreads();
        for (int i = 0; i < nv; ++i)
            acc = fmaf(wq[i][b], bf2f(hs[i][c]), acc);
    }
    atomicAdd(&out[b * 32 + c], acc / (float)ngenes);
}

extern "C" void kernel_launch(void* const* d_in, const int* in_sizes, int n_in,
                              void* d_out, int out_size, void* d_ws, size_t ws_size,
                              hipStream_t stream) {
    const float* x    = (const float*)d_in[0];
    const int*   ei   = (const int*)d_in[1];   // [2,E]: row at [0,E), col at [E,2E)
    const float* emb  = (const float*)d_in[3];
    const float* bias = (const float*)d_in[4];
    const float* W1   = (const float*)d_in[5];
    const float* b1   = (const float*)d_in[6];
    const float* W2   = (const float*)d_in[7];
    const float* b2   = (const float*)d_in[8];
    float* out = (float*)d_out;

    int N = in_sizes[0];
    int E = in_sizes[1] / 2;
    int ngenes = in_sizes[4];
    int nbuckets = (N + NPB - 1) / NPB;        // 2500
    int nsup = (nbuckets + 63) / 64;           // 40 (source supers)
    int nsupD = (N + 4095) / 4096;             // 40 (dest supers)
    int M = nbuckets + 64;

    char* pws = (char*)d_ws;
    auto carve = [&](size_t bytes) {
        void* r = (void*)pws;
        pws += (bytes + 255) & ~(size_t)255;
        return r;
    };
    u16*   h0      = (u16*)carve((size_t)N * 32 * 2);
    uint4* qA      = (uint4*)carve((size_t)N * 16);
    uint4* qB      = (uint4*)carve((size_t)N * 16);
    float* Amat    = (float*)carve((size_t)ngenes * 32 * 4);
    float* s1v     = (float*)carve(32 * 4);
    float* dinv    = (float*)carve((size_t)N * 4);
    float* afac    = (float*)carve((size_t)N * 4);
    float* rd      = (float*)carve((size_t)N * 4);
    int*   offsets = (int*)carve((size_t)(N + 1) * 4);
    int*   deg     = (int*)carve((size_t)N * 4);
    int*   bcnt    = (int*)carve((size_t)nbuckets * 4);
    int*   dscnt   = (int*)carve(64 * 4);
    int*   boff    = (int*)carve((size_t)(nbuckets + 1) * 4);
    int*   bCur    = (int*)carve((size_t)nbuckets * 4);
    int*   soff    = (int*)carve(65 * 4);
    int*   sCur    = (int*)carve(64 * 4);
    int*   dsoff   = (int*)carve(65 * 4);
    int*   dsCur   = (int*)carve(64 * 4);
    int*   pcnt    = (int*)carve((size_t)CNTB * M * 4);
    u32*   buf1    = (u32*)carve((size_t)E * 4);
    u32*   binned  = (u32*)carve((size_t)E * 4);
    int*   dsts    = (int*)carve((size_t)E * 4);
    u16*   dbuf    = (u16*)carve((size_t)E * 2);

    int nbN = (N + 255) / 256;
    int zlen = (int)(dscnt - deg) + 64;        // deg..bcnt..dscnt contiguous carves

    hipLaunchKernelGGL(k_zero_i, dim3((zlen + 255) / 256), dim3(256), 0, stream, deg, zlen);
    hipLaunchKernelGGL(k_cnt, dim3(CNTB), dim3(256), M * 4, stream, ei, E, pcnt, nbuckets);
    hipLaunchKernelGGL(k_merge, dim3((M + 255) / 256, MSEG), dim3(256), 0, stream,
                       pcnt, M, nbuckets, bcnt, dscnt);
    hipLaunchKernelGGL(k_scanB, dim3(1), dim3(1024), 0, stream,
                       bcnt, nbuckets, dscnt, boff, bCur, soff, sCur, dsoff, dsCur,
                       offsets, N, E, nsup, nsupD);
    hipLaunchKernelGGL(k_part, dim3((E + PCHUNK - 1) / PCHUNK), dim3(512), 0, stream,
                       ei, E, sCur, dsCur, buf1, dbuf);
    hipLaunchKernelGGL(k_dhist, dim3(nsupD * DHCHUNK), dim3(256), 0, stream,
                       dbuf, dsoff, deg, N);
    hipLaunchKernelGGL(k_p2, dim3(nsup * SPB), dim3(256), 0, stream, buf1, soff, bCur, binned);
    hipLaunchKernelGGL(k_sort, dim3(nbuckets), dim3(256), 0, stream,
                       binned, boff, offsets, dsts, N);
    hipLaunchKernelGGL(k_AW, dim3((ngenes + 7) / 8), dim3(256), 0, stream, emb, W1, Amat, s1v, ngenes);
    hipLaunchKernelGGL(k_h0, dim3(nbN), dim3(256), 0, stream,
                       x, Amat, bias, s1v, b1, W2, b2, deg, dinv, afac, rd,
                       (uint4*)h0, qA, out, out_size, N, ngenes);

    const uint4* qin = qA;
    for (int it = 0; it < 10; ++it) {
        uint4* qo = (it & 1) ? qA : qB;
        hipLaunchKernelGGL(k_prop8, dim3(nbN), dim3(256), 0, stream,
                           qin, qo, afac, dinv, offsets, dsts, N, ngenes);
        qin = qo;
    }

    hipLaunchKernelGGL(k_out, dim3((N + OUT_CHUNK - 1) / OUT_CHUNK), dim3(256), 0, stream,
                       qin, h0, rd, out, N, ngenes);
}